// Round 7
// baseline (793.278 us; speedup 1.0000x reference)
//
#include <hip/hip_runtime.h>

#define NBATCH 8
#define NXCD 8

// Read the physical XCD (XCC) id: hwreg id=20, offset=0, size=4 bits.
// imm = ((size-1)<<11) | (offset<<6) | id = (3<<11) | 20 = 6164.
__device__ __forceinline__ int xcc_id() {
    return __builtin_amdgcn_s_getreg(6164) & (NXCD - 1);
}

// Workgroup-scope relaxed float add: allows the RMW to be performed in the
// local XCD's L2 (no cross-XCD coherence round-trip / HBM write-through).
// Safe here because each accumulator copy is only ever touched by one XCD.
__device__ __forceinline__ void xadd(float* p, float v) {
    __hip_atomic_fetch_add(p, v, __ATOMIC_RELAXED, __HIP_MEMORY_SCOPE_WORKGROUP);
}

// ---------------------------------------------------------------------------
// Shared geometry: cotangent weights per the reference.
// ---------------------------------------------------------------------------
__device__ __forceinline__ void cot_weights(
    float x0, float y0, float z0, float x1, float y1, float z1,
    float x2, float y2, float z2, float& w0, float& w1, float& w2)
{
    const float EPSf = 1e-10f;
    float dx, dy, dz;
    dx = x1 - x2; dy = y1 - y2; dz = z1 - z2;
    float l1 = sqrtf(dx * dx + dy * dy + dz * dz);   // |v2 - v3|
    dx = x2 - x0; dy = y2 - y0; dz = z2 - z0;
    float l2 = sqrtf(dx * dx + dy * dy + dz * dz);   // |v3 - v1|
    dx = x0 - x1; dy = y0 - y1; dz = z0 - z1;
    float l3 = sqrtf(dx * dx + dy * dy + dz * dz);   // |v1 - v2|

    float sp = (l1 + l2 + l3) * 0.5f;
    float inside = sp * (sp - l1) * (sp - l2) * (sp - l3);
    inside = fmaxf(inside, 0.0f);
    float A = 2.0f * sqrtf(inside);
    float denom = A + EPSf;

    float l1s = l1 * l1, l2s = l2 * l2, l3s = l3 * l3;
    w0 = (l2s + l3s - l1s) / denom * 0.25f;  // edge (v2,v3)
    w1 = (l1s + l3s - l2s) / denom * 0.25f;  // edge (v3,v1)
    w2 = (l1s + l2s - l3s) / denom * 0.25f;  // edge (v1,v2)
    if (A == 0.0f) { w0 = 0.0f; w1 = 0.0f; w2 = 0.0f; }
}

// ---------------------------------------------------------------------------
// Path X: per-XCD private accumulators. acc8 = 8 copies of (BN*3) floats.
// Each block adds only into copy xcc_id() -> atomics stay XCD-local.
// Degree folded: contribution to vertex a is w_ab*(Pb-Pa) + w_ac*(Pc-Pa).
// ---------------------------------------------------------------------------
__global__ void __launch_bounds__(256) cot_face_xcd(
    const float* __restrict__ V,    // (B*N*3)
    const int*   __restrict__ F,    // (B*Fc*3)
    float*       __restrict__ acc8, // NXCD * (B*N*3), zeroed
    int N, int Fc, int BN3)
{
    int idx = blockIdx.x * blockDim.x + threadIdx.x;
    int total = NBATCH * Fc;
    if (idx >= total) return;

    float* acc = acc8 + (size_t)xcc_id() * BN3;

    int b = idx / Fc;
    size_t f3 = (size_t)idx * 3;
    int i0 = F[f3 + 0];
    int i1 = F[f3 + 1];
    int i2 = F[f3 + 2];
    int vb = b * N;
    int g0 = vb + i0, g1 = vb + i1, g2 = vb + i2;

    const float* P0 = V + (size_t)g0 * 3;
    const float* P1 = V + (size_t)g1 * 3;
    const float* P2 = V + (size_t)g2 * 3;
    float x0 = P0[0], y0 = P0[1], z0 = P0[2];
    float x1 = P1[0], y1 = P1[1], z1 = P1[2];
    float x2 = P2[0], y2 = P2[1], z2 = P2[2];

    float w0, w1, w2;
    cot_weights(x0, y0, z0, x1, y1, z1, x2, y2, z2, w0, w1, w2);

    xadd(&acc[(size_t)g0 * 3 + 0], w1 * (x2 - x0) + w2 * (x1 - x0));
    xadd(&acc[(size_t)g0 * 3 + 1], w1 * (y2 - y0) + w2 * (y1 - y0));
    xadd(&acc[(size_t)g0 * 3 + 2], w1 * (z2 - z0) + w2 * (z1 - z0));
    xadd(&acc[(size_t)g1 * 3 + 0], w0 * (x2 - x1) + w2 * (x0 - x1));
    xadd(&acc[(size_t)g1 * 3 + 1], w0 * (y2 - y1) + w2 * (y0 - y1));
    xadd(&acc[(size_t)g1 * 3 + 2], w0 * (z2 - z1) + w2 * (z0 - z1));
    xadd(&acc[(size_t)g2 * 3 + 0], w0 * (x1 - x2) + w1 * (x0 - x2));
    xadd(&acc[(size_t)g2 * 3 + 1], w0 * (y1 - y2) + w1 * (y0 - y2));
    xadd(&acc[(size_t)g2 * 3 + 2], w0 * (z1 - z2) + w1 * (z0 - z2));
}

// Sum the 8 XCD-private copies into the output. Fully coalesced.
__global__ void __launch_bounds__(256) cot_reduce8(
    const float* __restrict__ acc8,
    float*       __restrict__ out,
    int BN3)
{
    int i = blockIdx.x * blockDim.x + threadIdx.x;
    if (i >= BN3) return;
    float s = 0.0f;
#pragma unroll
    for (int x = 0; x < NXCD; ++x)
        s += acc8[(size_t)x * BN3 + i];
    out[i] = s;
}

// ---------------------------------------------------------------------------
// Fallback A: 64-bit CAS packed (x,y) + f32 z into float4-stride acc (round-2).
// ---------------------------------------------------------------------------
__device__ __forceinline__ void atomic_add_f2(unsigned long long* addr,
                                              unsigned long long seed,
                                              float ax, float ay) {
    unsigned long long old = seed;
    while (true) {
        float lo = __uint_as_float((unsigned)(old & 0xffffffffull));
        float hi = __uint_as_float((unsigned)(old >> 32));
        lo += ax; hi += ay;
        unsigned long long nv =
            ((unsigned long long)__float_as_uint(hi) << 32) | (unsigned long long)__float_as_uint(lo);
        unsigned long long ret = atomicCAS(addr, old, nv);
        if (ret == old) break;
        old = ret;
    }
}

__global__ void __launch_bounds__(256) cot_face_cas(
    const float* __restrict__ V,
    const int*   __restrict__ F,
    char*        __restrict__ acc, // (B*N) * 16B {x,y,z,pad}
    int N, int Fc)
{
    int idx = blockIdx.x * blockDim.x + threadIdx.x;
    int total = NBATCH * Fc;
    if (idx >= total) return;

    int b = idx / Fc;
    size_t f3 = (size_t)idx * 3;
    int i0 = F[f3 + 0];
    int i1 = F[f3 + 1];
    int i2 = F[f3 + 2];
    int vb = b * N;
    int g0 = vb + i0, g1 = vb + i1, g2 = vb + i2;

    unsigned long long* xy0 = (unsigned long long*)(acc + (size_t)g0 * 16);
    unsigned long long* xy1 = (unsigned long long*)(acc + (size_t)g1 * 16);
    unsigned long long* xy2 = (unsigned long long*)(acc + (size_t)g2 * 16);
    unsigned long long s0 = *(volatile unsigned long long*)xy0;
    unsigned long long s1 = *(volatile unsigned long long*)xy1;
    unsigned long long s2 = *(volatile unsigned long long*)xy2;

    const float* P0 = V + (size_t)g0 * 3;
    const float* P1 = V + (size_t)g1 * 3;
    const float* P2 = V + (size_t)g2 * 3;
    float x0 = P0[0], y0 = P0[1], z0 = P0[2];
    float x1 = P1[0], y1 = P1[1], z1 = P1[2];
    float x2 = P2[0], y2 = P2[1], z2 = P2[2];

    float w0, w1, w2;
    cot_weights(x0, y0, z0, x1, y1, z1, x2, y2, z2, w0, w1, w2);

    atomic_add_f2(xy0, s0, w1 * (x2 - x0) + w2 * (x1 - x0), w1 * (y2 - y0) + w2 * (y1 - y0));
    atomic_add_f2(xy1, s1, w0 * (x2 - x1) + w2 * (x0 - x1), w0 * (y2 - y1) + w2 * (y0 - y1));
    atomic_add_f2(xy2, s2, w0 * (x1 - x2) + w1 * (x0 - x2), w0 * (y1 - y2) + w1 * (y0 - y2));
    atomicAdd((float*)(acc + (size_t)g0 * 16 + 8), w1 * (z2 - z0) + w2 * (z1 - z0));
    atomicAdd((float*)(acc + (size_t)g1 * 16 + 8), w0 * (z2 - z1) + w2 * (z0 - z1));
    atomicAdd((float*)(acc + (size_t)g2 * 16 + 8), w0 * (z1 - z2) + w1 * (z0 - z2));
}

__global__ void __launch_bounds__(256) cot_repack(
    const float4* __restrict__ acc,
    float*        __restrict__ out,
    int BN)
{
    int v = blockIdx.x * blockDim.x + threadIdx.x;
    if (v >= BN) return;
    float4 a = acc[v];
    size_t o = (size_t)v * 3;
    out[o + 0] = a.x;
    out[o + 1] = a.y;
    out[o + 2] = a.z;
}

// ---------------------------------------------------------------------------
// Fallback B: 9 device-scope float atomics straight into d_out.
// ---------------------------------------------------------------------------
__global__ void __launch_bounds__(256) cot_face_add9(
    const float* __restrict__ V,
    const int*   __restrict__ F,
    float*       __restrict__ out,
    int N, int Fc)
{
    int idx = blockIdx.x * blockDim.x + threadIdx.x;
    int total = NBATCH * Fc;
    if (idx >= total) return;

    int b = idx / Fc;
    size_t f3 = (size_t)idx * 3;
    int i0 = F[f3 + 0];
    int i1 = F[f3 + 1];
    int i2 = F[f3 + 2];
    int vb = b * N;
    int g0 = vb + i0, g1 = vb + i1, g2 = vb + i2;

    const float* P0 = V + (size_t)g0 * 3;
    const float* P1 = V + (size_t)g1 * 3;
    const float* P2 = V + (size_t)g2 * 3;
    float x0 = P0[0], y0 = P0[1], z0 = P0[2];
    float x1 = P1[0], y1 = P1[1], z1 = P1[2];
    float x2 = P2[0], y2 = P2[1], z2 = P2[2];

    float w0, w1, w2;
    cot_weights(x0, y0, z0, x1, y1, z1, x2, y2, z2, w0, w1, w2);

    atomicAdd(&out[(size_t)g0 * 3 + 0], w1 * (x2 - x0) + w2 * (x1 - x0));
    atomicAdd(&out[(size_t)g0 * 3 + 1], w1 * (y2 - y0) + w2 * (y1 - y0));
    atomicAdd(&out[(size_t)g0 * 3 + 2], w1 * (z2 - z0) + w2 * (z1 - z0));
    atomicAdd(&out[(size_t)g1 * 3 + 0], w0 * (x2 - x1) + w2 * (x0 - x1));
    atomicAdd(&out[(size_t)g1 * 3 + 1], w0 * (y2 - y1) + w2 * (y0 - y1));
    atomicAdd(&out[(size_t)g1 * 3 + 2], w0 * (z2 - z1) + w2 * (z0 - z1));
    atomicAdd(&out[(size_t)g2 * 3 + 0], w0 * (x1 - x2) + w1 * (x0 - x2));
    atomicAdd(&out[(size_t)g2 * 3 + 1], w0 * (y1 - y2) + w1 * (y0 - y2));
    atomicAdd(&out[(size_t)g2 * 3 + 2], w0 * (z1 - z2) + w1 * (z0 - z2));
}

extern "C" void kernel_launch(void* const* d_in, const int* in_sizes, int n_in,
                              void* d_out, int out_size, void* d_ws, size_t ws_size,
                              hipStream_t stream) {
    const float* V = (const float*)d_in[0];
    const int*   F = (const int*)d_in[1];
    float* out = (float*)d_out;

    int BN3 = in_sizes[0];            // B*N*3
    int N   = BN3 / (NBATCH * 3);
    int Fc  = in_sizes[1] / (NBATCH * 3);
    int BN  = NBATCH * N;

    int totalF = NBATCH * Fc;
    int fblocks = (totalF + 255) / 256;

    size_t need_xcd = (size_t)NXCD * BN3 * sizeof(float);   // ~76.8 MB
    size_t need_cas = (size_t)BN * 16;                      // ~12.8 MB

    if (ws_size >= need_xcd) {
        // Path X: XCD-private accumulators, workgroup-scope atomics.
        hipMemsetAsync(d_ws, 0, need_xcd, stream);
        cot_face_xcd<<<fblocks, 256, 0, stream>>>(V, F, (float*)d_ws, N, Fc, BN3);
        int rblocks = (BN3 + 255) / 256;
        cot_reduce8<<<rblocks, 256, 0, stream>>>((const float*)d_ws, out, BN3);
    } else if (ws_size >= need_cas) {
        // Path A: packed CAS accumulation in ws, then repack.
        hipMemsetAsync(d_ws, 0, need_cas, stream);
        cot_face_cas<<<fblocks, 256, 0, stream>>>(V, F, (char*)d_ws, N, Fc);
        int vblocks = (BN + 255) / 256;
        cot_repack<<<vblocks, 256, 0, stream>>>((const float4*)d_ws, out, BN);
    } else {
        // Path B: 9 device-scope atomics into d_out.
        hipMemsetAsync(d_out, 0, (size_t)BN3 * sizeof(float), stream);
        cot_face_add9<<<fblocks, 256, 0, stream>>>(V, F, out, N, Fc);
    }
}

// Round 8
// 298.826 us; speedup vs baseline: 2.6546x; 2.6546x over previous
//
#include <hip/hip_runtime.h>

#define NBATCH 8
#define RANGE  5120   // vertices per LDS tile: 5120*3*4B = 60 KiB (static-LDS safe)
#define NSEG   3      // face-list segments -> partial output buffers

// ---------------------------------------------------------------------------
// Cotangent weights per the reference (Heron, EPS guard, A==0 -> 0).
// ---------------------------------------------------------------------------
__device__ __forceinline__ void cot_weights(
    float x0, float y0, float z0, float x1, float y1, float z1,
    float x2, float y2, float z2, float& w0, float& w1, float& w2)
{
    const float EPSf = 1e-10f;
    float dx, dy, dz;
    dx = x1 - x2; dy = y1 - y2; dz = z1 - z2;
    float l1 = sqrtf(dx * dx + dy * dy + dz * dz);   // |v2 - v3|
    dx = x2 - x0; dy = y2 - y0; dz = z2 - z0;
    float l2 = sqrtf(dx * dx + dy * dy + dz * dz);   // |v3 - v1|
    dx = x0 - x1; dy = y0 - y1; dz = z0 - z1;
    float l3 = sqrtf(dx * dx + dy * dy + dz * dz);   // |v1 - v2|

    float sp = (l1 + l2 + l3) * 0.5f;
    float inside = sp * (sp - l1) * (sp - l2) * (sp - l3);
    inside = fmaxf(inside, 0.0f);
    float A = 2.0f * sqrtf(inside);
    float denom = A + EPSf;

    float l1s = l1 * l1, l2s = l2 * l2, l3s = l3 * l3;
    w0 = (l2s + l3s - l1s) / denom * 0.25f;  // edge (v2,v3)
    w1 = (l1s + l3s - l2s) / denom * 0.25f;  // edge (v3,v1)
    w2 = (l1s + l2s - l3s) / denom * 0.25f;  // edge (v1,v2)
    if (A == 0.0f) { w0 = 0.0f; w1 = 0.0f; w2 = 0.0f; }
}

// LDS-scope f32 add (ds_add_f32): off-fabric, high throughput.
__device__ __forceinline__ void ladd(float* p, float v) {
    __hip_atomic_fetch_add(p, v, __ATOMIC_RELAXED, __HIP_MEMORY_SCOPE_WORKGROUP);
}

// ---------------------------------------------------------------------------
// Gather kernel: block = (batch, vertex-range, face-segment).
// Scans its segment of the batch's faces; accumulates degree-folded
// contributions for corners inside its vertex range into LDS; writes the
// tile coalesced (atomic-free) into partial buffer s.
// batch = blockIdx.x % 8: under round-robin block->XCD dispatch this keeps
// one batch's F+V (3.6 MB) resident in one XCD's 4 MB L2 (heuristic only).
// ---------------------------------------------------------------------------
__global__ void __launch_bounds__(256) cot_gather(
    const float* __restrict__ V,    // (B*N*3)
    const int*   __restrict__ F,    // (B*Fc*3)
    float*       __restrict__ part, // NSEG * BN3 floats (fully written)
    int N, int Fc, int BN3)
{
    __shared__ float lacc[RANGE * 3];

    int nr = (N + RANGE - 1) / RANGE;
    int b  = blockIdx.x % NBATCH;
    int t  = blockIdx.x / NBATCH;
    int r  = t / NSEG;
    int s  = t % NSEG;
    if (r >= nr) return;

    int lo = r * RANGE;
    int hi = min(lo + RANGE, N);
    unsigned rlen = (unsigned)(hi - lo);
    int len3 = (hi - lo) * 3;

    for (int i = threadIdx.x; i < RANGE * 3; i += blockDim.x) lacc[i] = 0.0f;
    __syncthreads();

    int fps = (Fc + NSEG - 1) / NSEG;
    int f0 = s * fps;
    int f1 = min(f0 + fps, Fc);

    const int*   Fb = F + (size_t)b * Fc * 3;
    const float* Vb = V + (size_t)b * N * 3;

    for (int f = f0 + (int)threadIdx.x; f < f1; f += (int)blockDim.x) {
        size_t f3 = (size_t)f * 3;
        int i0 = Fb[f3 + 0];
        int i1 = Fb[f3 + 1];
        int i2 = Fb[f3 + 2];
        unsigned u0 = (unsigned)(i0 - lo);
        unsigned u1 = (unsigned)(i1 - lo);
        unsigned u2 = (unsigned)(i2 - lo);
        bool in0 = u0 < rlen, in1 = u1 < rlen, in2 = u2 < rlen;
        if (!(in0 || in1 || in2)) continue;

        const float* P0 = Vb + (size_t)i0 * 3;
        const float* P1 = Vb + (size_t)i1 * 3;
        const float* P2 = Vb + (size_t)i2 * 3;
        float x0 = P0[0], y0 = P0[1], z0 = P0[2];
        float x1 = P1[0], y1 = P1[1], z1 = P1[2];
        float x2 = P2[0], y2 = P2[1], z2 = P2[2];

        float w0, w1, w2;
        cot_weights(x0, y0, z0, x1, y1, z1, x2, y2, z2, w0, w1, w2);

        // Degree-folded: c(a) = w_ab*(Pb - Pa) + w_ac*(Pc - Pa)
        if (in0) {
            ladd(&lacc[u0 * 3 + 0], w1 * (x2 - x0) + w2 * (x1 - x0));
            ladd(&lacc[u0 * 3 + 1], w1 * (y2 - y0) + w2 * (y1 - y0));
            ladd(&lacc[u0 * 3 + 2], w1 * (z2 - z0) + w2 * (z1 - z0));
        }
        if (in1) {
            ladd(&lacc[u1 * 3 + 0], w0 * (x2 - x1) + w2 * (x0 - x1));
            ladd(&lacc[u1 * 3 + 1], w0 * (y2 - y1) + w2 * (y0 - y1));
            ladd(&lacc[u1 * 3 + 2], w0 * (z2 - z1) + w2 * (z0 - z1));
        }
        if (in2) {
            ladd(&lacc[u2 * 3 + 0], w0 * (x1 - x2) + w1 * (x0 - x2));
            ladd(&lacc[u2 * 3 + 1], w0 * (y1 - y2) + w1 * (y0 - y2));
            ladd(&lacc[u2 * 3 + 2], w0 * (z1 - z2) + w1 * (z0 - z2));
        }
    }
    __syncthreads();

    // Coalesced, atomic-free write of the tile into partial buffer s.
    float* dst = part + (size_t)s * BN3 + ((size_t)b * N + lo) * 3;
    for (int i = threadIdx.x; i < len3; i += blockDim.x) dst[i] = lacc[i];
}

// ---------------------------------------------------------------------------
// Merge the NSEG partials -> out. float4 path (BN3 % 4 == 0) + scalar path.
// ---------------------------------------------------------------------------
__global__ void __launch_bounds__(256) cot_merge4(
    const float* __restrict__ part, float* __restrict__ out, int BN3)
{
    int i = blockIdx.x * blockDim.x + threadIdx.x;
    int n4 = BN3 >> 2;
    if (i >= n4) return;
    float4 a = ((const float4*)part)[i];
#pragma unroll
    for (int s = 1; s < NSEG; ++s) {
        float4 p = ((const float4*)(part + (size_t)s * BN3))[i];
        a.x += p.x; a.y += p.y; a.z += p.z; a.w += p.w;
    }
    ((float4*)out)[i] = a;
}

__global__ void __launch_bounds__(256) cot_merge1(
    const float* __restrict__ part, float* __restrict__ out, int BN3)
{
    int i = blockIdx.x * blockDim.x + threadIdx.x;
    if (i >= BN3) return;
    float v = part[i];
#pragma unroll
    for (int s = 1; s < NSEG; ++s) v += part[(size_t)s * BN3 + i];
    out[i] = v;
}

// ---------------------------------------------------------------------------
// Fallback (ws too small): 9 device-scope float atomics into d_out.
// ---------------------------------------------------------------------------
__global__ void __launch_bounds__(256) cot_face_add9(
    const float* __restrict__ V,
    const int*   __restrict__ F,
    float*       __restrict__ out,
    int N, int Fc)
{
    int idx = blockIdx.x * blockDim.x + threadIdx.x;
    int total = NBATCH * Fc;
    if (idx >= total) return;

    int b = idx / Fc;
    size_t f3 = (size_t)idx * 3;
    int i0 = F[f3 + 0];
    int i1 = F[f3 + 1];
    int i2 = F[f3 + 2];
    int vb = b * N;
    int g0 = vb + i0, g1 = vb + i1, g2 = vb + i2;

    const float* P0 = V + (size_t)g0 * 3;
    const float* P1 = V + (size_t)g1 * 3;
    const float* P2 = V + (size_t)g2 * 3;
    float x0 = P0[0], y0 = P0[1], z0 = P0[2];
    float x1 = P1[0], y1 = P1[1], z1 = P1[2];
    float x2 = P2[0], y2 = P2[1], z2 = P2[2];

    float w0, w1, w2;
    cot_weights(x0, y0, z0, x1, y1, z1, x2, y2, z2, w0, w1, w2);

    atomicAdd(&out[(size_t)g0 * 3 + 0], w1 * (x2 - x0) + w2 * (x1 - x0));
    atomicAdd(&out[(size_t)g0 * 3 + 1], w1 * (y2 - y0) + w2 * (y1 - y0));
    atomicAdd(&out[(size_t)g0 * 3 + 2], w1 * (z2 - z0) + w2 * (z1 - z0));
    atomicAdd(&out[(size_t)g1 * 3 + 0], w0 * (x2 - x1) + w2 * (x0 - x1));
    atomicAdd(&out[(size_t)g1 * 3 + 1], w0 * (y2 - y1) + w2 * (y0 - y1));
    atomicAdd(&out[(size_t)g1 * 3 + 2], w0 * (z2 - z1) + w2 * (z0 - z1));
    atomicAdd(&out[(size_t)g2 * 3 + 0], w0 * (x1 - x2) + w1 * (x0 - x2));
    atomicAdd(&out[(size_t)g2 * 3 + 1], w0 * (y1 - y2) + w1 * (y0 - y2));
    atomicAdd(&out[(size_t)g2 * 3 + 2], w0 * (z1 - z2) + w1 * (z0 - z2));
}

extern "C" void kernel_launch(void* const* d_in, const int* in_sizes, int n_in,
                              void* d_out, int out_size, void* d_ws, size_t ws_size,
                              hipStream_t stream) {
    const float* V = (const float*)d_in[0];
    const int*   F = (const int*)d_in[1];
    float* out = (float*)d_out;

    int BN3 = in_sizes[0];            // B*N*3
    int N   = BN3 / (NBATCH * 3);
    int Fc  = in_sizes[1] / (NBATCH * 3);

    size_t need = (size_t)NSEG * BN3 * sizeof(float);   // 28.8 MB partials

    if (ws_size >= need) {
        int nr = (N + RANGE - 1) / RANGE;
        int gblocks = NBATCH * nr * NSEG;
        cot_gather<<<gblocks, 256, 0, stream>>>(V, F, (float*)d_ws, N, Fc, BN3);
        if ((BN3 & 3) == 0) {
            int mblocks = ((BN3 >> 2) + 255) / 256;
            cot_merge4<<<mblocks, 256, 0, stream>>>((const float*)d_ws, out, BN3);
        } else {
            int mblocks = (BN3 + 255) / 256;
            cot_merge1<<<mblocks, 256, 0, stream>>>((const float*)d_ws, out, BN3);
        }
    } else {
        hipMemsetAsync(d_out, 0, (size_t)BN3 * sizeof(float), stream);
        int totalF = NBATCH * Fc;
        int fblocks = (totalF + 255) / 256;
        cot_face_add9<<<fblocks, 256, 0, stream>>>(V, F, out, N, Fc);
    }
}

// Round 9
// 168.181 us; speedup vs baseline: 4.7168x; 1.7768x over previous
//
#include <hip/hip_runtime.h>

#define NBATCH 8
#define NSEG   4      // face-list segments -> partial buffers

#define RANGE_BIG  13312   // 13312*3*4 = 159744 B dynamic LDS (1 block/CU)
#define RANGE_SM   5120    // 5120*3*4  = 61440 B static LDS  (2 blocks/CU)

// Packed triples (align 4) so LLVM merges to global_load_dwordx3.
struct I3 { int a, b, c; };
struct P3 { float x, y, z; };

// ---------------------------------------------------------------------------
// Cotangent weights per the reference (Heron, EPS guard, A==0 -> 0).
// ---------------------------------------------------------------------------
__device__ __forceinline__ void cot_weights(
    const P3& p0, const P3& p1, const P3& p2,
    float& w0, float& w1, float& w2)
{
    const float EPSf = 1e-10f;
    float dx, dy, dz;
    dx = p1.x - p2.x; dy = p1.y - p2.y; dz = p1.z - p2.z;
    float l1 = sqrtf(dx * dx + dy * dy + dz * dz);   // |v2 - v3|
    dx = p2.x - p0.x; dy = p2.y - p0.y; dz = p2.z - p0.z;
    float l2 = sqrtf(dx * dx + dy * dy + dz * dz);   // |v3 - v1|
    dx = p0.x - p1.x; dy = p0.y - p1.y; dz = p0.z - p1.z;
    float l3 = sqrtf(dx * dx + dy * dy + dz * dz);   // |v1 - v2|

    float sp = (l1 + l2 + l3) * 0.5f;
    float inside = sp * (sp - l1) * (sp - l2) * (sp - l3);
    inside = fmaxf(inside, 0.0f);
    float A = 2.0f * sqrtf(inside);
    float denom = A + EPSf;

    float l1s = l1 * l1, l2s = l2 * l2, l3s = l3 * l3;
    w0 = (l2s + l3s - l1s) / denom * 0.25f;
    w1 = (l1s + l3s - l2s) / denom * 0.25f;
    w2 = (l1s + l2s - l3s) / denom * 0.25f;
    if (A == 0.0f) { w0 = 0.0f; w1 = 0.0f; w2 = 0.0f; }
}

// Shared gather body. lacc is an LDS accumulator of rlen*3 floats.
__device__ __forceinline__ void gather_body(
    const float* __restrict__ V, const int* __restrict__ F,
    float* __restrict__ part, float* lacc,
    int N, int Fc, int BN3, int range, int nr, int nthreads)
{
    int b  = blockIdx.x % NBATCH;
    int t  = blockIdx.x / NBATCH;
    int r  = t / NSEG;
    int s  = t % NSEG;
    if (r >= nr) return;

    int lo = r * range;
    int hi = min(lo + range, N);
    unsigned rlen = (unsigned)(hi - lo);
    int len3 = (hi - lo) * 3;

    for (int i = threadIdx.x; i < len3; i += nthreads) lacc[i] = 0.0f;
    __syncthreads();

    int fps = (Fc + NSEG - 1) / NSEG;
    int f0 = s * fps;
    int f1 = min(f0 + fps, Fc);

    const int*   Fb = F + (size_t)b * Fc * 3;
    const float* Vb = V + (size_t)b * N * 3;

    for (int f = f0 + (int)threadIdx.x; f < f1; f += nthreads) {
        I3 idx = *reinterpret_cast<const I3*>(Fb + (size_t)f * 3);   // dwordx3
        unsigned u0 = (unsigned)(idx.a - lo);
        unsigned u1 = (unsigned)(idx.b - lo);
        unsigned u2 = (unsigned)(idx.c - lo);
        bool in0 = u0 < rlen, in1 = u1 < rlen, in2 = u2 < rlen;
        if (!(in0 || in1 || in2)) continue;

        P3 p0 = *reinterpret_cast<const P3*>(Vb + (size_t)idx.a * 3); // dwordx3
        P3 p1 = *reinterpret_cast<const P3*>(Vb + (size_t)idx.b * 3);
        P3 p2 = *reinterpret_cast<const P3*>(Vb + (size_t)idx.c * 3);

        float w0, w1, w2;
        cot_weights(p0, p1, p2, w0, w1, w2);

        // Degree-folded: c(a) = w_ab*(Pb - Pa) + w_ac*(Pc - Pa)
        if (in0) {
            atomicAdd(&lacc[u0 * 3 + 0], w1 * (p2.x - p0.x) + w2 * (p1.x - p0.x));
            atomicAdd(&lacc[u0 * 3 + 1], w1 * (p2.y - p0.y) + w2 * (p1.y - p0.y));
            atomicAdd(&lacc[u0 * 3 + 2], w1 * (p2.z - p0.z) + w2 * (p1.z - p0.z));
        }
        if (in1) {
            atomicAdd(&lacc[u1 * 3 + 0], w0 * (p2.x - p1.x) + w2 * (p0.x - p1.x));
            atomicAdd(&lacc[u1 * 3 + 1], w0 * (p2.y - p1.y) + w2 * (p0.y - p1.y));
            atomicAdd(&lacc[u1 * 3 + 2], w0 * (p2.z - p1.z) + w2 * (p0.z - p1.z));
        }
        if (in2) {
            atomicAdd(&lacc[u2 * 3 + 0], w0 * (p1.x - p2.x) + w1 * (p0.x - p2.x));
            atomicAdd(&lacc[u2 * 3 + 1], w0 * (p1.y - p2.y) + w1 * (p0.y - p2.y));
            atomicAdd(&lacc[u2 * 3 + 2], w0 * (p1.z - p2.z) + w1 * (p0.z - p2.z));
        }
    }
    __syncthreads();

    float* dst = part + (size_t)s * BN3 + ((size_t)b * N + lo) * 3;
    for (int i = threadIdx.x; i < len3; i += nthreads) dst[i] = lacc[i];
}

// Big-range kernel: dynamic LDS (159744 B), 1024 threads, 1 block/CU.
__global__ void __launch_bounds__(1024, 1) cot_gather_big(
    const float* __restrict__ V, const int* __restrict__ F,
    float* __restrict__ part, int N, int Fc, int BN3)
{
    extern __shared__ float lacc_dyn[];
    int nr = (N + RANGE_BIG - 1) / RANGE_BIG;
    gather_body(V, F, part, lacc_dyn, N, Fc, BN3, RANGE_BIG, nr, 1024);
}

// Small-range kernel: static 60 KiB LDS, 512 threads, 2 blocks/CU.
__global__ void __launch_bounds__(512) cot_gather_sm(
    const float* __restrict__ V, const int* __restrict__ F,
    float* __restrict__ part, int N, int Fc, int BN3)
{
    __shared__ float lacc_st[RANGE_SM * 3];
    int nr = (N + RANGE_SM - 1) / RANGE_SM;
    gather_body(V, F, part, lacc_st, N, Fc, BN3, RANGE_SM, nr, 512);
}

// Merge NSEG partials -> out.
__global__ void __launch_bounds__(256) cot_merge4(
    const float* __restrict__ part, float* __restrict__ out, int BN3)
{
    int i = blockIdx.x * blockDim.x + threadIdx.x;
    int n4 = BN3 >> 2;
    if (i >= n4) return;
    float4 a = ((const float4*)part)[i];
#pragma unroll
    for (int s = 1; s < NSEG; ++s) {
        float4 p = ((const float4*)(part + (size_t)s * BN3))[i];
        a.x += p.x; a.y += p.y; a.z += p.z; a.w += p.w;
    }
    ((float4*)out)[i] = a;
}

__global__ void __launch_bounds__(256) cot_merge1(
    const float* __restrict__ part, float* __restrict__ out, int BN3)
{
    int i = blockIdx.x * blockDim.x + threadIdx.x;
    if (i >= BN3) return;
    float v = part[i];
#pragma unroll
    for (int s = 1; s < NSEG; ++s) v += part[(size_t)s * BN3 + i];
    out[i] = v;
}

// Ultimate fallback (tiny ws): 9 device-scope atomics into d_out.
__global__ void __launch_bounds__(256) cot_face_add9(
    const float* __restrict__ V, const int* __restrict__ F,
    float* __restrict__ out, int N, int Fc)
{
    int idx = blockIdx.x * blockDim.x + threadIdx.x;
    int total = NBATCH * Fc;
    if (idx >= total) return;

    int b = idx / Fc;
    I3 ix = *reinterpret_cast<const I3*>(F + (size_t)idx * 3);
    int vb = b * N;
    int g0 = vb + ix.a, g1 = vb + ix.b, g2 = vb + ix.c;

    P3 p0 = *reinterpret_cast<const P3*>(V + (size_t)g0 * 3);
    P3 p1 = *reinterpret_cast<const P3*>(V + (size_t)g1 * 3);
    P3 p2 = *reinterpret_cast<const P3*>(V + (size_t)g2 * 3);

    float w0, w1, w2;
    cot_weights(p0, p1, p2, w0, w1, w2);

    atomicAdd(&out[(size_t)g0 * 3 + 0], w1 * (p2.x - p0.x) + w2 * (p1.x - p0.x));
    atomicAdd(&out[(size_t)g0 * 3 + 1], w1 * (p2.y - p0.y) + w2 * (p1.y - p0.y));
    atomicAdd(&out[(size_t)g0 * 3 + 2], w1 * (p2.z - p0.z) + w2 * (p1.z - p0.z));
    atomicAdd(&out[(size_t)g1 * 3 + 0], w0 * (p2.x - p1.x) + w2 * (p0.x - p1.x));
    atomicAdd(&out[(size_t)g1 * 3 + 1], w0 * (p2.y - p1.y) + w2 * (p0.y - p1.y));
    atomicAdd(&out[(size_t)g1 * 3 + 2], w0 * (p2.z - p1.z) + w2 * (p0.z - p1.z));
    atomicAdd(&out[(size_t)g2 * 3 + 0], w0 * (p1.x - p2.x) + w1 * (p0.x - p2.x));
    atomicAdd(&out[(size_t)g2 * 3 + 1], w0 * (p1.y - p2.y) + w1 * (p0.y - p2.y));
    atomicAdd(&out[(size_t)g2 * 3 + 2], w0 * (p1.z - p2.z) + w1 * (p0.z - p2.z));
}

extern "C" void kernel_launch(void* const* d_in, const int* in_sizes, int n_in,
                              void* d_out, int out_size, void* d_ws, size_t ws_size,
                              hipStream_t stream) {
    const float* V = (const float*)d_in[0];
    const int*   F = (const int*)d_in[1];
    float* out = (float*)d_out;

    int BN3 = in_sizes[0];            // B*N*3
    int N   = BN3 / (NBATCH * 3);
    int Fc  = in_sizes[1] / (NBATCH * 3);

    size_t need = (size_t)NSEG * BN3 * sizeof(float);   // 38.4 MB partials

    if (ws_size >= need) {
        const int dynLds = RANGE_BIG * 3 * sizeof(float);  // 159744 B
        hipError_t attr_ok = hipFuncSetAttribute(
            reinterpret_cast<const void*>(cot_gather_big),
            hipFuncAttributeMaxDynamicSharedMemorySize, dynLds);

        if (attr_ok == hipSuccess) {
            int nr = (N + RANGE_BIG - 1) / RANGE_BIG;
            int gblocks = NBATCH * nr * NSEG;   // 8*8*4 = 256 at N=100k
            cot_gather_big<<<gblocks, 1024, dynLds, stream>>>(V, F, (float*)d_ws, N, Fc, BN3);
        } else {
            int nr = (N + RANGE_SM - 1) / RANGE_SM;
            int gblocks = NBATCH * nr * NSEG;   // 8*20*4 = 640
            cot_gather_sm<<<gblocks, 512, 0, stream>>>(V, F, (float*)d_ws, N, Fc, BN3);
        }

        if ((BN3 & 3) == 0) {
            int mblocks = ((BN3 >> 2) + 255) / 256;
            cot_merge4<<<mblocks, 256, 0, stream>>>((const float*)d_ws, out, BN3);
        } else {
            int mblocks = (BN3 + 255) / 256;
            cot_merge1<<<mblocks, 256, 0, stream>>>((const float*)d_ws, out, BN3);
        }
    } else {
        hipMemsetAsync(d_out, 0, (size_t)BN3 * sizeof(float), stream);
        int totalF = NBATCH * Fc;
        int fblocks = (totalF + 255) / 256;
        cot_face_add9<<<fblocks, 256, 0, stream>>>(V, F, out, N, Fc);
    }
}